// Round 8
// baseline (222.277 us; speedup 1.0000x reference)
//
#include <hip/hip_runtime.h>
#include <math.h>

#define BB 8
#define CC 256
#define HH 128
#define WW 128
#define PP 16384  // H*W

typedef __attribute__((ext_vector_type(8))) short bf16x8;
typedef __attribute__((ext_vector_type(4))) float f32x4;

// ---------------- ws layout (float offsets) ----------------
#define O_XNODE   0u          // B*C*H = 262144
#define O_T       262144u     // 262144
#define O_R       524288u     // Rh bf16 (262144 ushort)
#define O_CTX     786432u     // Ch bf16
#define O_GT      1048576u    // Gb bf16 (2097152 ushort)
#define O_ATTR    3145728u    // B*H*W = 131072
#define O_ATTC    3276800u    // 131072
#define O_UN      3407872u    // B*H*16 = 16384
#define O_SUP     3424256u    // B*H*64 = 65536
#define O_VALS    3555328u    // B*H*8 = 8192
#define O_DEG     3563520u    // 1024
#define O_USUM    3564544u    // 1024
#define O_TMSUM   3565568u    // 1024
#define O_TM      3566592u    // 1024
#define O_SIGMT   3567616u    // 1024
#define O_ALPHA   3568640u    // 2048
#define O_SC      3570688u    // 2048
#define O_AROW    3572736u    // 1024
#define O_ACOL    3573760u    // 1024
#define O_IDX     3574784u    // 8192 ints

__device__ __forceinline__ ushort f2b(float f) {
    unsigned u = __float_as_uint(f);
    unsigned r = (u + 0x7FFFu + ((u >> 16) & 1u)) >> 16;
    return (ushort)r;
}

__device__ __forceinline__ float bredSum256(float v, float* red) {
    int t = threadIdx.x, lane = t & 63, wv = t >> 6;
    for (int o = 32; o; o >>= 1) v += __shfl_xor(v, o);
    __syncthreads();
    if (lane == 0) red[wv] = v;
    __syncthreads();
    return red[0] + red[1] + red[2] + red[3];
}
__device__ __forceinline__ float bredMax256(float v, float* red) {
    int t = threadIdx.x, lane = t & 63, wv = t >> 6;
    for (int o = 32; o; o >>= 1) v = fmaxf(v, __shfl_xor(v, o));
    __syncthreads();
    if (lane == 0) red[wv] = v;
    __syncthreads();
    return fmaxf(fmaxf(red[0], red[1]), fmaxf(red[2], red[3]));
}

// ---------- kA: X_node mean over w  (+ merged G->bf16 convert in first 1024 blocks) ----------
__global__ __launch_bounds__(256) void kA(const float* __restrict__ x, float* __restrict__ Xnode,
                                          const float* __restrict__ G, ushort* __restrict__ Gb) {
    if (blockIdx.x < 1024) {
        int i = (blockIdx.x * 256 + threadIdx.x) * 8;
        float4 v0 = *(const float4*)&G[i];
        float4 v1 = *(const float4*)&G[i + 4];
        union { ushort us[8]; uint4 u4; } o;
        o.us[0] = f2b(v0.x); o.us[1] = f2b(v0.y); o.us[2] = f2b(v0.z); o.us[3] = f2b(v0.w);
        o.us[4] = f2b(v1.x); o.us[5] = f2b(v1.y); o.us[6] = f2b(v1.z); o.us[7] = f2b(v1.w);
        *(uint4*)&Gb[i] = o.u4;
        return;
    }
    int row = (blockIdx.x - 1024) * 4 + (threadIdx.x >> 6);
    int lane = threadIdx.x & 63;
    const float2 v = *(const float2*)&x[(size_t)row * 128 + lane * 2];
    float s = v.x + v.y;
    for (int o = 32; o; o >>= 1) s += __shfl_down(s, o);
    if (lane == 0) Xnode[row] = s * (1.0f / 128.0f);
}

// ---------- S1: Un, Usum, support (per b,h) ----------
__global__ __launch_bounds__(64) void kS1(const float* __restrict__ U, const float* __restrict__ Xnode,
                                          const float* __restrict__ reduce_w, const float* __restrict__ gcn_w,
                                          float* __restrict__ Un, float* __restrict__ Usum, float* __restrict__ sup) {
    int bh = blockIdx.x; int b = bh >> 7, h = bh & 127;
    int t = threadIdx.x;
    __shared__ float xr[64];
    float u = (t < 16) ? U[bh * 16 + t] : 0.f;
    float ss = u * u;
    for (int o = 8; o; o >>= 1) ss += __shfl_xor(ss, o, 16);
    float us = u;
    for (int o = 8; o; o >>= 1) us += __shfl_xor(us, o, 16);
    if (t < 16) Un[bh * 16 + t] = u / fmaxf(sqrtf(ss), 1e-12f);
    if (t == 0) Usum[bh] = us;
    float acc = 0.f;
    #pragma unroll
    for (int m = 0; m < 4; ++m)
        acc = fmaf(Xnode[((b * CC + t * 4 + m) << 7) + h], reduce_w[t * 4 + m], acc);
    xr[t] = acc;
    __syncthreads();
    float sp = 0.f;
    for (int g = 0; g < 64; ++g) sp = fmaf(xr[g], gcn_w[g * 64 + t], sp);
    sup[bh * 64 + t] = sp;
}

// ---------- S2: sim row + top-8 + deg (per b,i) ----------
__global__ __launch_bounds__(128) void kS2(const float* __restrict__ Un, float* __restrict__ vals,
                                           int* __restrict__ idxv, float* __restrict__ deg) {
    int bh = blockIdx.x; int b = bh >> 7;
    int t = threadIdx.x;
    __shared__ float uni[16];
    __shared__ unsigned long long wmax[2];
    if (t < 16) uni[t] = Un[bh * 16 + t];
    __syncthreads();
    const float* uj = Un + (b << 11) + t * 16;
    float s = 0.f;
    #pragma unroll
    for (int q = 0; q < 16; ++q) s = fmaf(uni[q], uj[q], s);
    float dsum = 0.f;
    for (int r = 0; r < 8; ++r) {
        unsigned m = __float_as_uint(s);
        m = (m & 0x80000000u) ? ~m : (m | 0x80000000u);
        unsigned long long key = ((unsigned long long)m << 32) | (unsigned)(0xFFFFFFFFu - (unsigned)t);
        for (int o = 32; o; o >>= 1) { unsigned long long ok = __shfl_xor(key, o); key = key > ok ? key : ok; }
        if ((t & 63) == 0) wmax[t >> 6] = key;
        __syncthreads();
        unsigned long long kk = wmax[0] > wmax[1] ? wmax[0] : wmax[1];
        __syncthreads();
        int jw = (int)(0xFFFFFFFFu - (unsigned)(kk & 0xFFFFFFFFu));
        unsigned mm = (unsigned)(kk >> 32);
        mm = (mm & 0x80000000u) ? (mm & 0x7FFFFFFFu) : ~mm;
        float vw = __uint_as_float(mm);
        dsum += vw;
        if (t == r) { vals[bh * 8 + r] = vw; idxv[bh * 8 + r] = jw; }
        if (t == jw) s = -3.4e38f;
    }
    if (t == 0) deg[bh] = dsum;
}

// ---------- S3: gout, T, tmsum, sigmt (per b,i) ----------
__global__ __launch_bounds__(64) void kS3(const float* __restrict__ vals, const int* __restrict__ idxv,
                                          const float* __restrict__ deg, const float* __restrict__ sup,
                                          const float* __restrict__ gcn_b, const float* __restrict__ expand_w,
                                          float* __restrict__ Tg,
                                          float* __restrict__ tmsum, float* __restrict__ sigmt) {
    int bh = blockIdx.x; int b = bh >> 7, i = bh & 127;
    int t = threadIdx.x;
    __shared__ float coef[8];
    __shared__ int id[8];
    if (t < 8) {
        int j = idxv[bh * 8 + t];
        float dv = vals[bh * 8 + t] * (1.f / sqrtf(deg[bh])) * (1.f / sqrtf(deg[(b << 7) + j]));
        coef[t] = dv; id[t] = j;
    }
    __syncthreads();
    float acc = gcn_b[t];
    #pragma unroll
    for (int q = 0; q < 8; ++q) acc = fmaf(coef[q], sup[((b << 7) + id[q]) * 64 + t], acc);
    float go = fmaxf(acc, 0.f);
    float e0 = expand_w[t * 4], e1 = expand_w[t * 4 + 1], e2 = expand_w[t * 4 + 2], e3 = expand_w[t * 4 + 3];
    Tg[((b * CC + t * 4 + 0) << 7) + i] = go * e0;
    Tg[((b * CC + t * 4 + 1) << 7) + i] = go * e1;
    Tg[((b * CC + t * 4 + 2) << 7) + i] = go * e2;
    Tg[((b * CC + t * 4 + 3) << 7) + i] = go * e3;
    float tms = fabsf(go) * (fabsf(e0) + fabsf(e1) + fabsf(e2) + fabsf(e3));
    float mtp = go * (e0 + e1 + e2 + e3);
    for (int o = 32; o; o >>= 1) { tms += __shfl_down(tms, o); mtp += __shfl_down(mtp, o); }
    if (t == 0) {
        tmsum[bh] = tms;
        sigmt[bh] = 1.f / (1.f + expf(-(mtp * (1.f / 256.f))));
    }
}

// ---------- S4: tm, z's, ch_rec/sig, sc, w4 -> arow/acol/alpha (per b) ----------
__global__ __launch_bounds__(256) void kS4(const float* __restrict__ Xnode, const float* __restrict__ Tg,
                                           const float* __restrict__ V, const float* __restrict__ S,
                                           const float* __restrict__ boast, const float* __restrict__ res_scale,
                                           const float* __restrict__ w_row, const float* __restrict__ w_col,
                                           const float* __restrict__ tmsum,
                                           float* __restrict__ tm, float* __restrict__ alpha, float* __restrict__ sc,
                                           float* __restrict__ arow, float* __restrict__ acol) {
    int b = blockIdx.x; int t = threadIdx.x;
    __shared__ float red[4];
    __shared__ float zc[256];
    __shared__ float zk[16];
    float tv = (t < 128) ? tmsum[(b << 7) + t] : -3.4e38f;
    float tmax = bredMax256(tv, red);
    if (t < 128) tm[(b << 7) + t] = tv / fmaxf(tmax, 1e-6f);
    const float* xn = Xnode + ((size_t)(b * CC + t) << 7);
    const float* tg = Tg + ((size_t)(b * CC + t) << 7);
    float zx = 0.f, zt = 0.f;
    for (int h = 0; h < 128; h += 4) {
        float4 a = *(const float4*)&xn[h];
        float4 bq = *(const float4*)&tg[h];
        zx += (a.x + a.y) + (a.z + a.w);
        zt += (bq.x + bq.y) + (bq.z + bq.w);
    }
    zx *= (1.f / 128.f); zt *= (1.f / 128.f);
    zc[t] = zx + 0.5f * zt;
    __syncthreads();
    if (t < 16) {
        float a = 0.f;
        for (int c = 0; c < 256; ++c) a = fmaf(zc[c], V[((b * CC + c) << 4) + t], a);
        zk[t] = a;
    }
    __syncthreads();
    float sumS = 0.f, sumz = 0.f;
    #pragma unroll
    for (int j = 0; j < 16; ++j) { sumS += S[(b << 4) + j]; sumz += zk[j]; }
    float Vz = 0.f, VS = 0.f;
    #pragma unroll
    for (int j = 0; j < 16; ++j) {
        float vv = V[((b * CC + t) << 4) + j];
        Vz = fmaf(vv, zk[j], Vz);
        VS = fmaf(vv, S[(b << 4) + j], VS);
    }
    float ch = (Vz * sumS + VS * sumz) * (1.f / 32.f);
    float sig = 1.f / (1.f + expf(-ch));
    float zm = bredMax256(zt, red);
    float e = expf(zt - zm);
    float es = bredSum256(e, red);
    sc[b * CC + t] = e / es;
    float ps = 0.f;
    for (int q = t; q < 272; q += 256) {
        float si = (q < 16) ? S[(b << 4) + q] : (q < 144 ? w_col[q - 16] : w_row[q - 144]);
        ps += si;
    }
    float ssum = bredSum256(ps, red);
    float l0 = ssum * boast[t];
    float l1 = ssum * boast[256 + t];
    float lm = bredMax256(fmaxf(l0, l1), red);
    float e0 = expf(l0 - lm), e1 = expf(l1 - lm);
    float esum = bredSum256(e0 + e1, red);
    float w40 = e0 / esum, w41 = e1 / esum;
    if (t < 128) arow[(b << 7) + t] = w40;
    else acol[(b << 7) + (t - 128)] = w40;
    alpha[b * CC + t] = res_scale[0] + w41 * sig;
}

// ---------- S5: merged row/col softmax ----------
__global__ __launch_bounds__(128) void kS5(const float* __restrict__ Usum, const float* __restrict__ w_row,
                                           const float* __restrict__ w_col, const float* __restrict__ tm,
                                           float* __restrict__ attr, float* __restrict__ attc) {
    __shared__ float red[2];
    int id = blockIdx.x;
    int t = threadIdx.x;
    if (id < BB * HH) {
        int bh = id;
        float l = Usum[bh] * w_row[t] + 0.5f * tm[bh];
        float m = l;
        for (int o = 32; o; o >>= 1) m = fmaxf(m, __shfl_xor(m, o));
        if ((t & 63) == 0) red[t >> 6] = m;
        __syncthreads();
        m = fmaxf(red[0], red[1]);
        __syncthreads();
        float e = expf(l - m);
        float s = e;
        for (int o = 32; o; o >>= 1) s += __shfl_xor(s, o);
        if ((t & 63) == 0) red[t >> 6] = s;
        __syncthreads();
        s = red[0] + red[1];
        attr[id * 128 + t] = e / s;
    } else {
        int bw = id - BB * HH; int b = bw >> 7, w = bw & 127;
        float l = Usum[(b << 7) + t] * w_col[w] + 0.5f * tm[(b << 7) + t];
        float m = l;
        for (int o = 32; o; o >>= 1) m = fmaxf(m, __shfl_xor(m, o));
        if ((t & 63) == 0) red[t >> 6] = m;
        __syncthreads();
        m = fmaxf(red[0], red[1]);
        __syncthreads();
        float e = expf(l - m);
        float s = e;
        for (int o = 32; o; o >>= 1) s += __shfl_xor(s, o);
        if ((t & 63) == 0) red[t >> 6] = s;
        __syncthreads();
        s = red[0] + red[1];
        attc[((b << 7) + t) * 128 + w] = e / s;
    }
}

// ---------- kR: R[b,c,h], Cctx[b,c,w] -> bf16  (LDS-tiled, coalesced) ----------
__global__ __launch_bounds__(256) void kR(const float* __restrict__ x, const float* __restrict__ attr,
                                          const float* __restrict__ attc, ushort* __restrict__ Rh,
                                          ushort* __restrict__ Ch) {
    int bc = blockIdx.x;
    int b = bc >> 8;
    int t = threadIdx.x;
    __shared__ float tile[64][132];
    __shared__ float rsum[64][5];
    __shared__ float cred[8][128];
    int wq = (t & 31) * 4;
    int hg = t >> 5;
    const float* xb  = x    + (size_t)bc * PP;
    const float* arb = attr + (size_t)b * PP;
    const float* acb = attc + (size_t)b * PP;
    float4 cacc = make_float4(0.f, 0.f, 0.f, 0.f);
    #pragma unroll
    for (int cchunk = 0; cchunk < 2; ++cchunk) {
        int h0 = cchunk * 64;
        #pragma unroll
        for (int i = 0; i < 8; ++i) {
            int hh = i * 8 + hg;
            int off = (h0 + hh) * 128 + wq;
            float4 xv  = *(const float4*)&xb[off];
            float4 ar4 = *(const float4*)&arb[off];
            float4 ac4 = *(const float4*)&acb[off];
            cacc.x = fmaf(ac4.x, xv.x, cacc.x);
            cacc.y = fmaf(ac4.y, xv.y, cacc.y);
            cacc.z = fmaf(ac4.z, xv.z, cacc.z);
            cacc.w = fmaf(ac4.w, xv.w, cacc.w);
            float4 pr;
            pr.x = ar4.x * xv.x; pr.y = ar4.y * xv.y; pr.z = ar4.z * xv.z; pr.w = ar4.w * xv.w;
            *(float4*)&tile[hh][wq] = pr;
        }
        __syncthreads();
        int hl = t & 63, q = t >> 6;
        float s = 0.f;
        #pragma unroll
        for (int j = 0; j < 8; ++j) {
            float4 v = *(const float4*)&tile[hl][q * 32 + j * 4];
            s += (v.x + v.y) + (v.z + v.w);
        }
        rsum[hl][q] = s;
        __syncthreads();
        if (t < 64) Rh[bc * 128 + h0 + t] = f2b(rsum[t][0] + rsum[t][1] + rsum[t][2] + rsum[t][3]);
        __syncthreads();
    }
    *(float4*)&cred[hg][wq] = cacc;
    __syncthreads();
    if (t < 128) {
        float s = 0.f;
        #pragma unroll
        for (int g = 0; g < 8; ++g) s += cred[g][t];
        Ch[bc * 128 + t] = f2b(s);
    }
}

// ---------- kF v4: half-size waves for TLP. block: 32c x 128p, wave: 16c x 64p ----------
// A = G (rows = p), B = R/C (rows = c). D: col=lane&15 -> c, row=4*(lane>>4)+reg -> p.
__global__ __launch_bounds__(256) void kF(const float* __restrict__ x, const ushort* __restrict__ Rh,
                                          const ushort* __restrict__ Ch, const ushort* __restrict__ Gb,
                                          const float* __restrict__ Tg, const float* __restrict__ alpha,
                                          const float* __restrict__ sc, const float* __restrict__ sigmt,
                                          const float* __restrict__ arow, const float* __restrict__ acol,
                                          float* __restrict__ out) {
    int b = blockIdx.z;
    int c0 = blockIdx.y * 32;
    int p0 = blockIdx.x * 128;
    int tid = threadIdx.x;
    int wid = tid >> 6, l = tid & 63;
    int lr = l & 15, lk = l >> 4;
    int pbase = p0 + (wid & 1) * 64;
    int cbase = c0 + (wid >> 1) * 16;
    int h = blockIdx.x;

    // prefetch x + per-c scalars (drain during the MFMA phase)
    int c = cbase + lr;
    size_t rowb = ((size_t)((b << 8) + c) << 14) + pbase + 4 * lk;
    f32x4 xv[4];
    #pragma unroll
    for (int m = 0; m < 4; ++m)
        xv[m] = *(const f32x4*)&x[rowb + 16 * m];
    float al = alpha[(b << 8) + c];
    float scv = sc[(b << 8) + c];
    float tgv = Tg[(((b << 8) + c) << 7) + h];
    float ar = arow[(b << 7) + h];
    float smt = sigmt[(b << 7) + h];
    int wloc = (wid & 1) * 64 + 4 * lk;
    f32x4 acw[4];
    #pragma unroll
    for (int m = 0; m < 4; ++m) acw[m] = *(const f32x4*)&acol[(b << 7) + wloc + 16 * m];

    f32x4 accR[4], accC[4];
    #pragma unroll
    for (int m = 0; m < 4; ++m) {
        accR[m] = (f32x4){0.f, 0.f, 0.f, 0.f};
        accC[m] = (f32x4){0.f, 0.f, 0.f, 0.f};
    }

    const ushort* Gbase = Gb + ((size_t)(pbase + lr) << 7);
    const ushort* Rbase = Rh + (((b << 8) + cbase + lr) << 7);
    const ushort* Cbase = Ch + (((b << 8) + cbase + lr) << 7);

    #pragma unroll
    for (int ks = 0; ks < 4; ++ks) {
        int ko = ks * 32 + lk * 8;
        bf16x8 ag0 = *(const bf16x8*)(Gbase + (0 << 11) + ko);
        bf16x8 ag1 = *(const bf16x8*)(Gbase + (1 << 11) + ko);
        bf16x8 ag2 = *(const bf16x8*)(Gbase + (2 << 11) + ko);
        bf16x8 ag3 = *(const bf16x8*)(Gbase + (3 << 11) + ko);
        bf16x8 bR = *(const bf16x8*)(Rbase + ko);
        bf16x8 bC = *(const bf16x8*)(Cbase + ko);
        accR[0] = __builtin_amdgcn_mfma_f32_16x16x32_bf16(ag0, bR, accR[0], 0, 0, 0);
        accR[1] = __builtin_amdgcn_mfma_f32_16x16x32_bf16(ag1, bR, accR[1], 0, 0, 0);
        accR[2] = __builtin_amdgcn_mfma_f32_16x16x32_bf16(ag2, bR, accR[2], 0, 0, 0);
        accR[3] = __builtin_amdgcn_mfma_f32_16x16x32_bf16(ag3, bR, accR[3], 0, 0, 0);
        accC[0] = __builtin_amdgcn_mfma_f32_16x16x32_bf16(ag0, bC, accC[0], 0, 0, 0);
        accC[1] = __builtin_amdgcn_mfma_f32_16x16x32_bf16(ag1, bC, accC[1], 0, 0, 0);
        accC[2] = __builtin_amdgcn_mfma_f32_16x16x32_bf16(ag2, bC, accC[2], 0, 0, 0);
        accC[3] = __builtin_amdgcn_mfma_f32_16x16x32_bf16(ag3, bC, accC[3], 0, 0, 0);
    }

    float tb = (scv + smt) * tgv;
    #pragma unroll
    for (int m = 0; m < 4; ++m) {
        f32x4 o;
        o[0] = fmaf(al, xv[m][0], fmaf(ar, accR[m][0], fmaf(acw[m][0], accC[m][0], ar * acw[m][0] * tb)));
        o[1] = fmaf(al, xv[m][1], fmaf(ar, accR[m][1], fmaf(acw[m][1], accC[m][1], ar * acw[m][1] * tb)));
        o[2] = fmaf(al, xv[m][2], fmaf(ar, accR[m][2], fmaf(acw[m][2], accC[m][2], ar * acw[m][2] * tb)));
        o[3] = fmaf(al, xv[m][3], fmaf(ar, accR[m][3], fmaf(acw[m][3], accC[m][3], ar * acw[m][3] * tb)));
        *(f32x4*)&out[rowb + 16 * m] = o;
    }
}

extern "C" void kernel_launch(void* const* d_in, const int* in_sizes, int n_in,
                              void* d_out, int out_size, void* d_ws, size_t ws_size,
                              hipStream_t stream) {
    const float* x        = (const float*)d_in[0];
    const float* U        = (const float*)d_in[1];
    const float* S        = (const float*)d_in[2];
    const float* V        = (const float*)d_in[3];
    const float* G        = (const float*)d_in[4];
    const float* w_row    = (const float*)d_in[5];
    const float* w_col    = (const float*)d_in[6];
    const float* boast    = (const float*)d_in[7];
    const float* res_scale= (const float*)d_in[8];
    const float* reduce_w = (const float*)d_in[9];
    const float* gcn_w    = (const float*)d_in[10];
    const float* gcn_b    = (const float*)d_in[11];
    const float* expand_w = (const float*)d_in[12];
    float* ws = (float*)d_ws;
    float* out = (float*)d_out;

    float* Xnode = ws + O_XNODE;
    float* Tg    = ws + O_T;
    ushort* Rh   = (ushort*)(ws + O_R);
    ushort* Ch   = (ushort*)(ws + O_CTX);
    ushort* Gb   = (ushort*)(ws + O_GT);
    float* attr  = ws + O_ATTR;
    float* attc  = ws + O_ATTC;
    float* Un    = ws + O_UN;
    float* sup   = ws + O_SUP;
    float* vals  = ws + O_VALS;
    float* deg   = ws + O_DEG;
    float* Usum  = ws + O_USUM;
    float* tmsum = ws + O_TMSUM;
    float* tm    = ws + O_TM;
    float* sigmt = ws + O_SIGMT;
    float* alpha = ws + O_ALPHA;
    float* sc    = ws + O_SC;
    float* arow  = ws + O_AROW;
    float* acol  = ws + O_ACOL;
    int*   idxv  = (int*)(ws + O_IDX);

    kA<<<1024 + BB * CC * HH / 4, 256, 0, stream>>>(x, Xnode, G, Gb);
    kS1<<<BB * HH, 64, 0, stream>>>(U, Xnode, reduce_w, gcn_w, Un, Usum, sup);
    kS2<<<BB * HH, 128, 0, stream>>>(Un, vals, idxv, deg);
    kS3<<<BB * HH, 64, 0, stream>>>(vals, idxv, deg, sup, gcn_b, expand_w, Tg, tmsum, sigmt);
    kS4<<<BB, 256, 0, stream>>>(Xnode, Tg, V, S, boast, res_scale, w_row, w_col, tmsum,
                                tm, alpha, sc, arow, acol);
    kS5<<<BB * HH + BB * WW, 128, 0, stream>>>(Usum, w_row, w_col, tm, attr, attc);
    kR<<<BB * CC, 256, 0, stream>>>(x, attr, attc, Rh, Ch);
    kF<<<dim3(PP / 128, CC / 32, BB), 256, 0, stream>>>(x, Rh, Ch, Gb, Tg, alpha, sc, sigmt,
                                                        arow, acol, out);
}

// Round 9
// 147.861 us; speedup vs baseline: 1.5033x; 1.5033x over previous
//
#include <hip/hip_runtime.h>
#include <math.h>

#define BB 8
#define CC 256
#define HH 128
#define WW 128
#define PP 16384  // H*W

typedef __attribute__((ext_vector_type(8))) short bf16x8;
typedef __attribute__((ext_vector_type(4))) float f32x4;

// ---------------- ws layout (float offsets) ----------------
#define O_XNODE   0u          // B*C*H = 262144
#define O_T       262144u     // 262144
#define O_R       524288u     // Rh bf16 (262144 ushort)
#define O_CTX     786432u     // Ch bf16
#define O_GT      1048576u    // Gb bf16 (2097152 ushort)
#define O_ATTR    3145728u    // B*H*W = 131072
#define O_ATTC    3276800u    // 131072
#define O_UN      3407872u    // B*H*16 = 16384
#define O_SUP     3424256u    // B*H*64 = 65536
#define O_VALS    3555328u    // B*H*8 = 8192
#define O_DEG     3563520u    // 1024
#define O_USUM    3564544u    // 1024
#define O_TMSUM   3565568u    // 1024
#define O_TM      3566592u    // 1024
#define O_SIGMT   3567616u    // 1024
#define O_ALPHA   3568640u    // 2048
#define O_SC      3570688u    // 2048
#define O_AROW    3572736u    // 1024
#define O_ACOL    3573760u    // 1024
#define O_IDX     3574784u    // 8192 ints

__device__ __forceinline__ ushort f2b(float f) {
    unsigned u = __float_as_uint(f);
    unsigned r = (u + 0x7FFFu + ((u >> 16) & 1u)) >> 16;
    return (ushort)r;
}

__device__ __forceinline__ float bredSum256(float v, float* red) {
    int t = threadIdx.x, lane = t & 63, wv = t >> 6;
    for (int o = 32; o; o >>= 1) v += __shfl_xor(v, o);
    __syncthreads();
    if (lane == 0) red[wv] = v;
    __syncthreads();
    return red[0] + red[1] + red[2] + red[3];
}
__device__ __forceinline__ float bredMax256(float v, float* red) {
    int t = threadIdx.x, lane = t & 63, wv = t >> 6;
    for (int o = 32; o; o >>= 1) v = fmaxf(v, __shfl_xor(v, o));
    __syncthreads();
    if (lane == 0) red[wv] = v;
    __syncthreads();
    return fmaxf(fmaxf(red[0], red[1]), fmaxf(red[2], red[3]));
}

// ---------- kA: G->bf16 convert (first 1024 blocks) + X_node mean (64 B/thread) ----------
__global__ __launch_bounds__(256) void kA(const float* __restrict__ x, float* __restrict__ Xnode,
                                          const float* __restrict__ G, ushort* __restrict__ Gb) {
    if (blockIdx.x < 1024) {
        int i = (blockIdx.x * 256 + threadIdx.x) * 8;
        float4 v0 = *(const float4*)&G[i];
        float4 v1 = *(const float4*)&G[i + 4];
        union { ushort us[8]; uint4 u4; } o;
        o.us[0] = f2b(v0.x); o.us[1] = f2b(v0.y); o.us[2] = f2b(v0.z); o.us[3] = f2b(v0.w);
        o.us[4] = f2b(v1.x); o.us[5] = f2b(v1.y); o.us[6] = f2b(v1.z); o.us[7] = f2b(v1.w);
        *(uint4*)&Gb[i] = o.u4;
        return;
    }
    int bid = blockIdx.x - 1024;              // 8192 blocks, 32 rows each
    int t = threadIdx.x;
    int row = bid * 32 + (t >> 3);
    int seg = t & 7;                          // 8 threads/row, 16 floats each
    const float4* p = (const float4*)&x[(size_t)row * 128 + seg * 16];
    float4 a = p[0], b4 = p[1], c4 = p[2], d4 = p[3];
    float s = ((a.x + a.y) + (a.z + a.w)) + ((b4.x + b4.y) + (b4.z + b4.w))
            + ((c4.x + c4.y) + (c4.z + c4.w)) + ((d4.x + d4.y) + (d4.z + d4.w));
    s += __shfl_xor(s, 1, 8);
    s += __shfl_xor(s, 2, 8);
    s += __shfl_xor(s, 4, 8);
    if (seg == 0) Xnode[row] = s * (1.0f / 128.0f);
}

// ---------- S1: Un, Usum, support (per b,h) ----------
__global__ __launch_bounds__(64) void kS1(const float* __restrict__ U, const float* __restrict__ Xnode,
                                          const float* __restrict__ reduce_w, const float* __restrict__ gcn_w,
                                          float* __restrict__ Un, float* __restrict__ Usum, float* __restrict__ sup) {
    int bh = blockIdx.x; int b = bh >> 7, h = bh & 127;
    int t = threadIdx.x;
    __shared__ float xr[64];
    float u = (t < 16) ? U[bh * 16 + t] : 0.f;
    float ss = u * u;
    for (int o = 8; o; o >>= 1) ss += __shfl_xor(ss, o, 16);
    float us = u;
    for (int o = 8; o; o >>= 1) us += __shfl_xor(us, o, 16);
    if (t < 16) Un[bh * 16 + t] = u / fmaxf(sqrtf(ss), 1e-12f);
    if (t == 0) Usum[bh] = us;
    float acc = 0.f;
    #pragma unroll
    for (int m = 0; m < 4; ++m)
        acc = fmaf(Xnode[((b * CC + t * 4 + m) << 7) + h], reduce_w[t * 4 + m], acc);
    xr[t] = acc;
    __syncthreads();
    float sp = 0.f;
    for (int g = 0; g < 64; ++g) sp = fmaf(xr[g], gcn_w[g * 64 + t], sp);
    sup[bh * 64 + t] = sp;
}

// ---------- S2: sim row + top-8 + deg (per b,i) ----------
__global__ __launch_bounds__(128) void kS2(const float* __restrict__ Un, float* __restrict__ vals,
                                           int* __restrict__ idxv, float* __restrict__ deg) {
    int bh = blockIdx.x; int b = bh >> 7;
    int t = threadIdx.x;
    __shared__ float uni[16];
    __shared__ unsigned long long wmax[2];
    if (t < 16) uni[t] = Un[bh * 16 + t];
    __syncthreads();
    const float* uj = Un + (b << 11) + t * 16;
    float s = 0.f;
    #pragma unroll
    for (int q = 0; q < 16; ++q) s = fmaf(uni[q], uj[q], s);
    float dsum = 0.f;
    for (int r = 0; r < 8; ++r) {
        unsigned m = __float_as_uint(s);
        m = (m & 0x80000000u) ? ~m : (m | 0x80000000u);
        unsigned long long key = ((unsigned long long)m << 32) | (unsigned)(0xFFFFFFFFu - (unsigned)t);
        for (int o = 32; o; o >>= 1) { unsigned long long ok = __shfl_xor(key, o); key = key > ok ? key : ok; }
        if ((t & 63) == 0) wmax[t >> 6] = key;
        __syncthreads();
        unsigned long long kk = wmax[0] > wmax[1] ? wmax[0] : wmax[1];
        __syncthreads();
        int jw = (int)(0xFFFFFFFFu - (unsigned)(kk & 0xFFFFFFFFu));
        unsigned mm = (unsigned)(kk >> 32);
        mm = (mm & 0x80000000u) ? (mm & 0x7FFFFFFFu) : ~mm;
        float vw = __uint_as_float(mm);
        dsum += vw;
        if (t == r) { vals[bh * 8 + r] = vw; idxv[bh * 8 + r] = jw; }
        if (t == jw) s = -3.4e38f;
    }
    if (t == 0) deg[bh] = dsum;
}

// ---------- S3: gout, T, tmsum, sigmt (per b,i) ----------
__global__ __launch_bounds__(64) void kS3(const float* __restrict__ vals, const int* __restrict__ idxv,
                                          const float* __restrict__ deg, const float* __restrict__ sup,
                                          const float* __restrict__ gcn_b, const float* __restrict__ expand_w,
                                          float* __restrict__ Tg,
                                          float* __restrict__ tmsum, float* __restrict__ sigmt) {
    int bh = blockIdx.x; int b = bh >> 7, i = bh & 127;
    int t = threadIdx.x;
    __shared__ float coef[8];
    __shared__ int id[8];
    if (t < 8) {
        int j = idxv[bh * 8 + t];
        float dv = vals[bh * 8 + t] * (1.f / sqrtf(deg[bh])) * (1.f / sqrtf(deg[(b << 7) + j]));
        coef[t] = dv; id[t] = j;
    }
    __syncthreads();
    float acc = gcn_b[t];
    #pragma unroll
    for (int q = 0; q < 8; ++q) acc = fmaf(coef[q], sup[((b << 7) + id[q]) * 64 + t], acc);
    float go = fmaxf(acc, 0.f);
    float e0 = expand_w[t * 4], e1 = expand_w[t * 4 + 1], e2 = expand_w[t * 4 + 2], e3 = expand_w[t * 4 + 3];
    Tg[((b * CC + t * 4 + 0) << 7) + i] = go * e0;
    Tg[((b * CC + t * 4 + 1) << 7) + i] = go * e1;
    Tg[((b * CC + t * 4 + 2) << 7) + i] = go * e2;
    Tg[((b * CC + t * 4 + 3) << 7) + i] = go * e3;
    float tms = fabsf(go) * (fabsf(e0) + fabsf(e1) + fabsf(e2) + fabsf(e3));
    float mtp = go * (e0 + e1 + e2 + e3);
    for (int o = 32; o; o >>= 1) { tms += __shfl_down(tms, o); mtp += __shfl_down(mtp, o); }
    if (t == 0) {
        tmsum[bh] = tms;
        sigmt[bh] = 1.f / (1.f + expf(-(mtp * (1.f / 256.f))));
    }
}

// ---------- S4: tm, z's, ch_rec/sig, sc, w4 -> arow/acol/alpha (per b) ----------
__global__ __launch_bounds__(256) void kS4(const float* __restrict__ Xnode, const float* __restrict__ Tg,
                                           const float* __restrict__ V, const float* __restrict__ S,
                                           const float* __restrict__ boast, const float* __restrict__ res_scale,
                                           const float* __restrict__ w_row, const float* __restrict__ w_col,
                                           const float* __restrict__ tmsum,
                                           float* __restrict__ tm, float* __restrict__ alpha, float* __restrict__ sc,
                                           float* __restrict__ arow, float* __restrict__ acol) {
    int b = blockIdx.x; int t = threadIdx.x;
    __shared__ float red[4];
    __shared__ float zc[256];
    __shared__ float zk[16];
    float tv = (t < 128) ? tmsum[(b << 7) + t] : -3.4e38f;
    float tmax = bredMax256(tv, red);
    if (t < 128) tm[(b << 7) + t] = tv / fmaxf(tmax, 1e-6f);
    const float* xn = Xnode + ((size_t)(b * CC + t) << 7);
    const float* tg = Tg + ((size_t)(b * CC + t) << 7);
    float zx = 0.f, zt = 0.f;
    for (int h = 0; h < 128; h += 4) {
        float4 a = *(const float4*)&xn[h];
        float4 bq = *(const float4*)&tg[h];
        zx += (a.x + a.y) + (a.z + a.w);
        zt += (bq.x + bq.y) + (bq.z + bq.w);
    }
    zx *= (1.f / 128.f); zt *= (1.f / 128.f);
    zc[t] = zx + 0.5f * zt;
    __syncthreads();
    if (t < 16) {
        float a = 0.f;
        for (int c = 0; c < 256; ++c) a = fmaf(zc[c], V[((b * CC + c) << 4) + t], a);
        zk[t] = a;
    }
    __syncthreads();
    float sumS = 0.f, sumz = 0.f;
    #pragma unroll
    for (int j = 0; j < 16; ++j) { sumS += S[(b << 4) + j]; sumz += zk[j]; }
    float Vz = 0.f, VS = 0.f;
    #pragma unroll
    for (int j = 0; j < 16; ++j) {
        float vv = V[((b * CC + t) << 4) + j];
        Vz = fmaf(vv, zk[j], Vz);
        VS = fmaf(vv, S[(b << 4) + j], VS);
    }
    float ch = (Vz * sumS + VS * sumz) * (1.f / 32.f);
    float sig = 1.f / (1.f + expf(-ch));
    float zm = bredMax256(zt, red);
    float e = expf(zt - zm);
    float es = bredSum256(e, red);
    sc[b * CC + t] = e / es;
    float ps = 0.f;
    for (int q = t; q < 272; q += 256) {
        float si = (q < 16) ? S[(b << 4) + q] : (q < 144 ? w_col[q - 16] : w_row[q - 144]);
        ps += si;
    }
    float ssum = bredSum256(ps, red);
    float l0 = ssum * boast[t];
    float l1 = ssum * boast[256 + t];
    float lm = bredMax256(fmaxf(l0, l1), red);
    float e0 = expf(l0 - lm), e1 = expf(l1 - lm);
    float esum = bredSum256(e0 + e1, red);
    float w40 = e0 / esum, w41 = e1 / esum;
    if (t < 128) arow[(b << 7) + t] = w40;
    else acol[(b << 7) + (t - 128)] = w40;
    alpha[b * CC + t] = res_scale[0] + w41 * sig;
}

// ---------- S5: merged row/col softmax ----------
__global__ __launch_bounds__(128) void kS5(const float* __restrict__ Usum, const float* __restrict__ w_row,
                                           const float* __restrict__ w_col, const float* __restrict__ tm,
                                           float* __restrict__ attr, float* __restrict__ attc) {
    __shared__ float red[2];
    int id = blockIdx.x;
    int t = threadIdx.x;
    if (id < BB * HH) {
        int bh = id;
        float l = Usum[bh] * w_row[t] + 0.5f * tm[bh];
        float m = l;
        for (int o = 32; o; o >>= 1) m = fmaxf(m, __shfl_xor(m, o));
        if ((t & 63) == 0) red[t >> 6] = m;
        __syncthreads();
        m = fmaxf(red[0], red[1]);
        __syncthreads();
        float e = expf(l - m);
        float s = e;
        for (int o = 32; o; o >>= 1) s += __shfl_xor(s, o);
        if ((t & 63) == 0) red[t >> 6] = s;
        __syncthreads();
        s = red[0] + red[1];
        attr[id * 128 + t] = e / s;
    } else {
        int bw = id - BB * HH; int b = bw >> 7, w = bw & 127;
        float l = Usum[(b << 7) + t] * w_col[w] + 0.5f * tm[(b << 7) + t];
        float m = l;
        for (int o = 32; o; o >>= 1) m = fmaxf(m, __shfl_xor(m, o));
        if ((t & 63) == 0) red[t >> 6] = m;
        __syncthreads();
        m = fmaxf(red[0], red[1]);
        __syncthreads();
        float e = expf(l - m);
        float s = e;
        for (int o = 32; o; o >>= 1) s += __shfl_xor(s, o);
        if ((t & 63) == 0) red[t >> 6] = s;
        __syncthreads();
        s = red[0] + red[1];
        attc[((b << 7) + t) * 128 + w] = e / s;
    }
}

// ---------- kR: R[b,c,h], Cctx[b,c,w] -> bf16  (LDS-tiled, coalesced) ----------
__global__ __launch_bounds__(256) void kR(const float* __restrict__ x, const float* __restrict__ attr,
                                          const float* __restrict__ attc, ushort* __restrict__ Rh,
                                          ushort* __restrict__ Ch) {
    int bc = blockIdx.x;
    int b = bc >> 8;
    int t = threadIdx.x;
    __shared__ float tile[64][132];
    __shared__ float rsum[64][5];
    __shared__ float cred[8][128];
    int wq = (t & 31) * 4;
    int hg = t >> 5;
    const float* xb  = x    + (size_t)bc * PP;
    const float* arb = attr + (size_t)b * PP;
    const float* acb = attc + (size_t)b * PP;
    float4 cacc = make_float4(0.f, 0.f, 0.f, 0.f);
    #pragma unroll
    for (int cchunk = 0; cchunk < 2; ++cchunk) {
        int h0 = cchunk * 64;
        #pragma unroll
        for (int i = 0; i < 8; ++i) {
            int hh = i * 8 + hg;
            int off = (h0 + hh) * 128 + wq;
            float4 xv  = *(const float4*)&xb[off];
            float4 ar4 = *(const float4*)&arb[off];
            float4 ac4 = *(const float4*)&acb[off];
            cacc.x = fmaf(ac4.x, xv.x, cacc.x);
            cacc.y = fmaf(ac4.y, xv.y, cacc.y);
            cacc.z = fmaf(ac4.z, xv.z, cacc.z);
            cacc.w = fmaf(ac4.w, xv.w, cacc.w);
            float4 pr;
            pr.x = ar4.x * xv.x; pr.y = ar4.y * xv.y; pr.z = ar4.z * xv.z; pr.w = ar4.w * xv.w;
            *(float4*)&tile[hh][wq] = pr;
        }
        __syncthreads();
        int hl = t & 63, q = t >> 6;
        float s = 0.f;
        #pragma unroll
        for (int j = 0; j < 8; ++j) {
            float4 v = *(const float4*)&tile[hl][q * 32 + j * 4];
            s += (v.x + v.y) + (v.z + v.w);
        }
        rsum[hl][q] = s;
        __syncthreads();
        if (t < 64) Rh[bc * 128 + h0 + t] = f2b(rsum[t][0] + rsum[t][1] + rsum[t][2] + rsum[t][3]);
        __syncthreads();
    }
    *(float4*)&cred[hg][wq] = cacc;
    __syncthreads();
    if (t < 128) {
        float s = 0.f;
        #pragma unroll
        for (int g = 0; g < 8; ++g) s += cred[g][t];
        Ch[bc * 128 + t] = f2b(s);
    }
}

// ---------- kF v5: LDS-staged operands + MFMA + fused epilogue ----------
// block: 64c x 128p (one h row), 4 waves (2p x 2c); A=G(rows=p), B=R/C(rows=c).
// LDS layout: [row][col16 ^ (row&7)] (16B granules) -> balanced banks on b128 read & write.
__global__ __launch_bounds__(256) void kF(const float* __restrict__ x, const ushort* __restrict__ Rh,
                                          const ushort* __restrict__ Ch, const ushort* __restrict__ Gb,
                                          const float* __restrict__ Tg, const float* __restrict__ alpha,
                                          const float* __restrict__ sc, const float* __restrict__ sigmt,
                                          const float* __restrict__ arow, const float* __restrict__ acol,
                                          float* __restrict__ out) {
    __shared__ ushort gL[16384];   // 128 rows x 128 k bf16, swizzled (32 KB)
    __shared__ ushort rL[8192];    // 64 rows (16 KB)
    __shared__ ushort cL[8192];    // 64 rows (16 KB)
    int b = blockIdx.z;
    int c0 = blockIdx.y * 64;
    int p0 = blockIdx.x * 128;
    int tid = threadIdx.x;
    int wid = tid >> 6, l = tid & 63;
    int lr = l & 15, lk = l >> 4;
    int pbase = p0 + (wid & 1) * 64;
    int cwave = (wid >> 1) * 32;
    int h = blockIdx.x;

    // x + per-c scalar prefetch (issued first; drains during staging/MFMA)
    f32x4 xv[2][4];
    float al[2], scv[2], tgv[2];
    size_t rowb[2];
    #pragma unroll
    for (int n = 0; n < 2; ++n) {
        int c = c0 + cwave + 16 * n + lr;
        rowb[n] = ((size_t)((b << 8) + c) << 14) + pbase + 4 * lk;
        #pragma unroll
        for (int m = 0; m < 4; ++m)
            xv[n][m] = *(const f32x4*)&x[rowb[n] + 16 * m];
        al[n] = alpha[(b << 8) + c];
        scv[n] = sc[(b << 8) + c];
        tgv[n] = Tg[(((b << 8) + c) << 7) + h];
    }
    float ar = arow[(b << 7) + h];
    float smt = sigmt[(b << 7) + h];
    int wloc = (wid & 1) * 64 + 4 * lk;
    f32x4 acw[4];
    #pragma unroll
    for (int m = 0; m < 4; ++m) acw[m] = *(const f32x4*)&acol[(b << 7) + wloc + 16 * m];

    // ---- stage tiles: coalesced uint4 reads, swizzled ds_write ----
    {
        const uint4* gsrc = (const uint4*)(Gb + (size_t)p0 * 128);
        #pragma unroll
        for (int it = 0; it < 8; ++it) {
            int j = it * 256 + tid;                  // 16B granule 0..2047
            uint4 v = gsrc[j];
            int row = j >> 4, col16 = j & 15;
            *(uint4*)&gL[row * 128 + ((col16 ^ (row & 7)) << 3)] = v;
        }
        const uint4* rsrc = (const uint4*)(Rh + (((b << 8) + c0) << 7));
        const uint4* csrc = (const uint4*)(Ch + (((b << 8) + c0) << 7));
        #pragma unroll
        for (int it = 0; it < 4; ++it) {
            int j = it * 256 + tid;                  // 0..1023
            uint4 vr = rsrc[j];
            uint4 vc = csrc[j];
            int row = j >> 4, col16 = j & 15;
            int d = row * 128 + ((col16 ^ (row & 7)) << 3);
            *(uint4*)&rL[d] = vr;
            *(uint4*)&cL[d] = vc;
        }
    }
    __syncthreads();

    f32x4 accR[4][2], accC[4][2];
    #pragma unroll
    for (int m = 0; m < 4; ++m)
        #pragma unroll
        for (int n = 0; n < 2; ++n) {
            accR[m][n] = (f32x4){0.f, 0.f, 0.f, 0.f};
            accC[m][n] = (f32x4){0.f, 0.f, 0.f, 0.f};
        }

    int swz = lr & 7;                                // row&7 == lr&7 for all row bases (mult of 16)
    int growb = (wid & 1) * 64 + lr;
    int crowb = cwave + lr;
    #pragma unroll
    for (int ks = 0; ks < 4; ++ks) {
        int col = ((ks * 4 + lk) ^ swz) << 3;        // swizzled ushort column offset
        bf16x8 ag0 = *(const bf16x8*)&gL[(growb +  0) * 128 + col];
        bf16x8 ag1 = *(const bf16x8*)&gL[(growb + 16) * 128 + col];
        bf16x8 ag2 = *(const bf16x8*)&gL[(growb + 32) * 128 + col];
        bf16x8 ag3 = *(const bf16x8*)&gL[(growb + 48) * 128 + col];
        bf16x8 bR0 = *(const bf16x8*)&rL[(crowb +  0) * 128 + col];
        bf16x8 bR1 = *(const bf16x8*)&rL[(crowb + 16) * 128 + col];
        bf16x8 bC0 = *(const bf16x8*)&cL[(crowb +  0) * 128 + col];
        bf16x8 bC1 = *(const bf16x8*)&cL[(crowb + 16) * 128 + col];
        accR[0][0] = __builtin_amdgcn_mfma_f32_16x16x32_bf16(ag0, bR0, accR[0][0], 0, 0, 0);
        accR[0][1] = __builtin_amdgcn_mfma_f32_16x16x32_bf16(ag0, bR1, accR[0][1], 0, 0, 0);
        accR[1][0] = __builtin_amdgcn_mfma_f32_16x16x32_bf16(ag1, bR0, accR[1][0], 0, 0, 0);
        accR[1][1] = __builtin_amdgcn_mfma_f32_16x16x32_bf16(ag1, bR1, accR[1][1], 0, 0, 0);
        accR[2][0] = __builtin_amdgcn_mfma_f32_16x16x32_bf16(ag2, bR0, accR[2][0], 0, 0, 0);
        accR[2][1] = __builtin_amdgcn_mfma_f32_16x16x32_bf16(ag2, bR1, accR[2][1], 0, 0, 0);
        accR[3][0] = __builtin_amdgcn_mfma_f32_16x16x32_bf16(ag3, bR0, accR[3][0], 0, 0, 0);
        accR[3][1] = __builtin_amdgcn_mfma_f32_16x16x32_bf16(ag3, bR1, accR[3][1], 0, 0, 0);
        accC[0][0] = __builtin_amdgcn_mfma_f32_16x16x32_bf16(ag0, bC0, accC[0][0], 0, 0, 0);
        accC[0][1] = __builtin_amdgcn_mfma_f32_16x16x32_bf16(ag0, bC1, accC[0][1], 0, 0, 0);
        accC[1][0] = __builtin_amdgcn_mfma_f32_16x16x32_bf16(ag1, bC0, accC[1][0], 0, 0, 0);
        accC[1][1] = __builtin_amdgcn_mfma_f32_16x16x32_bf16(ag1, bC1, accC[1][1], 0, 0, 0);
        accC[2][0] = __builtin_amdgcn_mfma_f32_16x16x32_bf16(ag2, bC0, accC[2][0], 0, 0, 0);
        accC[2][1] = __builtin_amdgcn_mfma_f32_16x16x32_bf16(ag2, bC1, accC[2][1], 0, 0, 0);
        accC[3][0] = __builtin_amdgcn_mfma_f32_16x16x32_bf16(ag3, bC0, accC[3][0], 0, 0, 0);
        accC[3][1] = __builtin_amdgcn_mfma_f32_16x16x32_bf16(ag3, bC1, accC[3][1], 0, 0, 0);
    }

    #pragma unroll
    for (int n = 0; n < 2; ++n) {
        float tb = (scv[n] + smt) * tgv[n];
        #pragma unroll
        for (int m = 0; m < 4; ++m) {
            f32x4 o;
            o[0] = fmaf(al[n], xv[n][m][0], fmaf(ar, accR[m][n][0], fmaf(acw[m][0], accC[m][n][0], ar * acw[m][0] * tb)));
            o[1] = fmaf(al[n], xv[n][m][1], fmaf(ar, accR[m][n][1], fmaf(acw[m][1], accC[m][n][1], ar * acw[m][1] * tb)));
            o[2] = fmaf(al[n], xv[n][m][2], fmaf(ar, accR[m][n][2], fmaf(acw[m][2], accC[m][n][2], ar * acw[m][2] * tb)));
            o[3] = fmaf(al[n], xv[n][m][3], fmaf(ar, accR[m][n][3], fmaf(acw[m][3], accC[m][n][3], ar * acw[m][3] * tb)));
            *(f32x4*)&out[rowb[n] + 16 * m] = o;
        }
    }
}

extern "C" void kernel_launch(void* const* d_in, const int* in_sizes, int n_in,
                              void* d_out, int out_size, void* d_ws, size_t ws_size,
                              hipStream_t stream) {
    const float* x        = (const float*)d_in[0];
    const float* U        = (const float*)d_in[1];
    const float* S        = (const float*)d_in[2];
    const float* V        = (const float*)d_in[3];
    const float* G        = (const float*)d_in[4];
    const float* w_row    = (const float*)d_in[5];
    const float* w_col    = (const float*)d_in[6];
    const float* boast    = (const float*)d_in[7];
    const float* res_scale= (const float*)d_in[8];
    const float* reduce_w = (const float*)d_in[9];
    const float* gcn_w    = (const float*)d_in[10];
    const float* gcn_b    = (const float*)d_in[11];
    const float* expand_w = (const float*)d_in[12];
    float* ws = (float*)d_ws;
    float* out = (float*)d_out;

    float* Xnode = ws + O_XNODE;
    float* Tg    = ws + O_T;
    ushort* Rh   = (ushort*)(ws + O_R);
    ushort* Ch   = (ushort*)(ws + O_CTX);
    ushort* Gb   = (ushort*)(ws + O_GT);
    float* attr  = ws + O_ATTR;
    float* attc  = ws + O_ATTC;
    float* Un    = ws + O_UN;
    float* sup   = ws + O_SUP;
    float* vals  = ws + O_VALS;
    float* deg   = ws + O_DEG;
    float* Usum  = ws + O_USUM;
    float* tmsum = ws + O_TMSUM;
    float* tm    = ws + O_TM;
    float* sigmt = ws + O_SIGMT;
    float* alpha = ws + O_ALPHA;
    float* sc    = ws + O_SC;
    float* arow  = ws + O_AROW;
    float* acol  = ws + O_ACOL;
    int*   idxv  = (int*)(ws + O_IDX);

    kA<<<1024 + BB * CC * HH / 32, 256, 0, stream>>>(x, Xnode, G, Gb);
    kS1<<<BB * HH, 64, 0, stream>>>(U, Xnode, reduce_w, gcn_w, Un, Usum, sup);
    kS2<<<BB * HH, 128, 0, stream>>>(Un, vals, idxv, deg);
    kS3<<<BB * HH, 64, 0, stream>>>(vals, idxv, deg, sup, gcn_b, expand_w, Tg, tmsum, sigmt);
    kS4<<<BB, 256, 0, stream>>>(Xnode, Tg, V, S, boast, res_scale, w_row, w_col, tmsum,
                                tm, alpha, sc, arow, acol);
    kS5<<<BB * HH + BB * WW, 128, 0, stream>>>(Usum, w_row, w_col, tm, attr, attc);
    kR<<<BB * CC, 256, 0, stream>>>(x, attr, attc, Rh, Ch);
    kF<<<dim3(PP / 128, CC / 64, BB), 256, 0, stream>>>(x, Rh, Ch, Gb, Tg, alpha, sc, sigmt,
                                                        arow, acol, out);
}